// Round 4
// baseline (341.898 us; speedup 1.0000x reference)
//
#include <hip/hip_runtime.h>

// MeanSquaredError3: heatmap MSE (d1) + offset-regression MSE (d2), scalar out.
//
// Round 4: one pair per THREAD (was: one pair per wave). R3 showed the
// wave-per-pair shape is chain-bound, not MLP-bound: a 6-deep serial
// ds_permute argmax (~800 cyc/pair) + per-pair broadcasts + 49/64-lane
// divergence dominate, so deeper h-prefetch was neutral. Now each thread owns
// one (b,j): streams its 49 float4s (stride-784 across lanes; 16B accesses
// never straddle 64B lines, L1 absorbs the 4x line reuse), fused per-element
// argmax (strict > = first occurrence) + branchless d1 accumulate with y/x
// folded to constants by full unroll. Zero shuffles / broadcasts / divergence
// in the hot loop. Depth-8 rotating buffer -> 8KB/wave in flight x 7 waves/CU.
// Reduction: wave shuffle (block=1 wave) -> per-block partials -> finish kernel.

#define COL 14
#define NJ 14
#define CELLS (COL * COL)     // 196
#define TPB 64                // one wave per block; 1792 blocks = 7/CU exactly
#define PFD 8                 // h-stream rotating-buffer depth (power of 2)
#define NEGINF -3.402823466e38f

__global__ __launch_bounds__(TPB)
void mse3_main(const float* __restrict__ outp, const float* __restrict__ tp,
               const float* __restrict__ vp, double* __restrict__ partial, int npair)
{
    __shared__ float Gs[CELLS];
    __shared__ float cminS[COL], cmaxS[COL];

    const int tid = threadIdx.x;

    // Build G exactly like the reference: w = exp(-0.5*k^2) fp64, normalized,
    // symmetric-padded identity convolution, accumulated fp64, cast to f32.
    for (int g = tid; g < CELLS; g += TPB) {
        const double wraw[9] = {3.3546262790251185e-4, 1.1108996538242306e-2,
                                1.353352832366127e-1,  6.065306597126334e-1, 1.0,
                                6.065306597126334e-1,  1.353352832366127e-1,
                                1.1108996538242306e-2, 3.3546262790251185e-4};
        const double Z = 2.5066208042307818;  // sum of wraw
        int gi = g / COL;
        int gj = g - COL * gi;
        double a = 0.0;
#pragma unroll
        for (int k = 0; k < 9; ++k) {
            int r = gi + k;  // row into symmetric-padded eye (22 rows)
            int m = (r < 4) ? (3 - r) : ((r < 18) ? (r - 4) : (31 - r));
            if (m == gj) a += wraw[k] / Z;
        }
        Gs[g] = (float)a;
    }
    __syncthreads();
    // Per-column min/max (all G entries > 0: outer-product min/max factorize;
    // fp multiply is monotone, so factored fp32 min/max == elementwise).
    if (tid < COL) {
        float mn = Gs[tid], mx = mn;
        for (int r = 1; r < COL; ++r) {
            float g = Gs[r * COL + tid];
            mn = fminf(mn, g);
            mx = fmaxf(mx, g);
        }
        cminS[tid] = mn;
        cmaxS[tid] = mx;
    }
    __syncthreads();

    const int p = blockIdx.x * TPB + tid;

    float s1 = 0.0f, s2 = 0.0f, cnt = 0.0f, n2 = 0.0f;

    if (p < npair) {
        const int b = p / NJ;
        const int j = p - NJ * b;
        const float4* hp4 = reinterpret_cast<const float4*>(
            outp + ((size_t)b * (3 * NJ) + j) * CELLS);

        // per-pair scalars (coalesced float2 loads across lanes)
        const float2 tv = reinterpret_cast<const float2*>(tp)[p];
        const float2 vv = reinterpret_cast<const float2*>(vp)[p];
        const int xi = (int)(tv.x * 14.0f);   // trunc toward 0, as astype(int32)
        const int yi = (int)(tv.y * 14.0f);
        const bool inb    = (xi >= 0) && (xi <= COL - 1) && (yi >= 0) && (yi <= COL - 1);
        const bool vis    = ((int)vv.x == 1);
        const bool scat   = vis && inb;
        const bool zeroed = vis && !inb;
        const float ve0   = zeroed ? 0.0f : vv.x;
        const float ve1   = zeroed ? 0.0f : vv.y;
        const bool vise   = ((int)ve0 == 1);
        const float vm    = vise ? 1.0f : 0.0f;
        const int xic = min(max(xi, 0), COL - 1);
        const int yic = min(max(yi, 0), COL - 1);

        const float mnv = cminS[yic] * cminS[xic];
        const float mxv = cmaxS[yic] * cmaxS[xic];
        const float A      = scat ? (1.0f / (mxv - mnv)) : 0.0f;
        const float mnAneg = -mnv * A;

        // Gaussian columns into registers (28 one-time LDS gathers);
        // fold A into gx so the hot loop is 1 fma for tt.
        float gyv[COL], gxA[COL];
#pragma unroll
        for (int y = 0; y < COL; ++y) gyv[y] = Gs[y * COL + yic];
#pragma unroll
        for (int x = 0; x < COL; ++x) gxA[x] = Gs[x * COL + xic] * A;

        float best = NEGINF;
        int bidx = 0;

        // depth-PFD rotating buffer over the 49 float4s of this pair's h tile
        float4 buf[PFD];
#pragma unroll
        for (int d = 0; d < PFD; ++d) buf[d] = hp4[d];

#pragma unroll
        for (int c = 0; c < 49; ++c) {
            float4 hv = buf[c & (PFD - 1)];
            if (c + PFD < 49) buf[c & (PFD - 1)] = hp4[c + PFD];
            const float h4[4] = {hv.x, hv.y, hv.z, hv.w};
#pragma unroll
            for (int q = 0; q < 4; ++q) {
                const int e = 4 * c + q;        // compile-time constant
                const int y = e / COL;
                const int x = e - COL * y;
                const float h = h4[q];
                if (h > best) { best = h; bidx = e; }   // cndmask pair; first max wins
                float ttv = fmaf(gyv[y], gxA[x], mnAneg); // 0 when !scat
                float d1 = h - ttv;
                if (e < COL) d1 *= vm;          // row-0 visibility mask
                s1 = fmaf(d1, d1, s1);
            }
        }

        // d2 epilogue: gather ox/oy at argmax (per-lane, independent loads)
        const float* base = outp + (size_t)b * (3 * NJ) * CELLS;
        const float ox = base[(size_t)(NJ + j) * CELLS + bidx];
        const float oy = base[(size_t)(2 * NJ + j) * CELLS + bidx];
        const int yc = bidx / COL;
        const int xc = bidx - COL * yc;
        const float SC = (float)(1.0 / 14.0);
        float dx = (ox + (float)xc) * SC - tv.x; dx *= ve0;
        float dy = (oy + (float)yc) * SC - tv.y; dy *= ve1;
        s2  = dx * dx + dy * dy;
        cnt = vise ? 1.0f : 0.0f;
        n2  = ve0 + ve1;
    }

    // block = one wave: shuffle reduce, write deterministic per-block partials
#pragma unroll
    for (int off = 32; off >= 1; off >>= 1) {
        s1  += __shfl_down(s1,  off, 64);
        s2  += __shfl_down(s2,  off, 64);
        cnt += __shfl_down(cnt, off, 64);
        n2  += __shfl_down(n2,  off, 64);
    }
    if (tid == 0) {
        double* o = partial + (size_t)blockIdx.x * 4;
        o[0] = (double)s1; o[1] = (double)s2;
        o[2] = (double)cnt; o[3] = (double)n2;
    }
}

__global__ __launch_bounds__(256)
void mse3_final(const double* __restrict__ partial, float* __restrict__ o, int nblk)
{
    __shared__ double p2[4][4];
    double a0 = 0, a1 = 0, a2 = 0, a3 = 0;
    for (int b = threadIdx.x; b < nblk; b += 256) {
        const double* q = partial + (size_t)b * 4;
        a0 += q[0]; a1 += q[1]; a2 += q[2]; a3 += q[3];
    }
#pragma unroll
    for (int off = 32; off >= 1; off >>= 1) {
        a0 += __shfl_down(a0, off, 64);
        a1 += __shfl_down(a1, off, 64);
        a2 += __shfl_down(a2, off, 64);
        a3 += __shfl_down(a3, off, 64);
    }
    const int lane = threadIdx.x & 63, wv = threadIdx.x >> 6;
    if (lane == 0) { p2[wv][0] = a0; p2[wv][1] = a1; p2[wv][2] = a2; p2[wv][3] = a3; }
    __syncthreads();
    if (threadIdx.x == 0) {
        double s1 = 0, s2 = 0, cn = 0, nn = 0;
        for (int i = 0; i < 4; ++i) {
            s1 += p2[i][0]; s2 += p2[i][1]; cn += p2[i][2]; nn += p2[i][3];
        }
        o[0] = (float)(s1 / cn + s2 / (0.5 * nn));  // d1 + d2
    }
}

extern "C" void kernel_launch(void* const* d_in, const int* in_sizes, int n_in,
                              void* d_out, int out_size, void* d_ws, size_t ws_size,
                              hipStream_t stream)
{
    const float* outp = (const float*)d_in[0];   // (B, 42, 14, 14) f32
    const float* tp   = (const float*)d_in[1];   // (B, 14, 2) f32
    const float* vp   = (const float*)d_in[2];   // (B, 14, 2) f32
    double* partial = (double*)d_ws;             // nblk*4 doubles (ws is huge)

    const int B = in_sizes[0] / (3 * NJ * CELLS);
    const int npair = B * NJ;                    // 114688
    const int nblk = (npair + TPB - 1) / TPB;    // 1792 = 7 blocks/CU exactly

    mse3_main<<<nblk, TPB, 0, stream>>>(outp, tp, vp, partial, npair);
    mse3_final<<<1, 256, 0, stream>>>(partial, (float*)d_out, nblk);
}